// Round 8
// baseline (626.436 us; speedup 1.0000x reference)
//
#include <hip/hip_runtime.h>
#include <hip/hip_bf16.h>

#define B_ 4
#define S_ 1024
#define D_ 1024
#define H_ 16
#define HD_ 64
#define OUT0_ 4194304ull   // B*S*D

typedef __hip_bfloat16 bf16;
typedef __attribute__((ext_vector_type(8))) short short8;
typedef __attribute__((ext_vector_type(4))) short short4v;
typedef __attribute__((ext_vector_type(4))) float f32x4;

#define MFMA16(a,b,c) __builtin_amdgcn_mfma_f32_16x16x32_bf16(a,b,c,0,0,0)
#define WAIT_LGKM0() __builtin_amdgcn_s_waitcnt(0xC07F)   // lgkmcnt(0), vm/exp unconstrained

__device__ __forceinline__ float b2f(bf16 x){ return __bfloat162float(x); }
__device__ __forceinline__ bf16  f2b(float x){ return __float2bfloat16(x); }
__device__ __forceinline__ short f2s(float x){ bf16 h = __float2bfloat16(x); return *reinterpret_cast<short*>(&h); }
__device__ __forceinline__ float s2f(short u){ return __uint_as_float(((unsigned)(unsigned short)u) << 16); }
__device__ __forceinline__ float ldin(const void* p, size_t i, int f32){
    return f32 ? ((const float*)p)[i] : b2f(((const bf16*)p)[i]);
}
__device__ __forceinline__ void stout(void* p, size_t i, int f32, float v){
    if (f32) ((float*)p)[i] = v; else ((bf16*)p)[i] = f2b(v);
}

// ---------------------------------------------------------------------------
// dtype probe (kept: established fp32 on this dataset, cheap and safe)
// ---------------------------------------------------------------------------
__global__ void dtype_probe(const unsigned int* __restrict__ q, int* __restrict__ flag)
{
    __shared__ int cnt[256];
    const int t = threadIdx.x;
    const unsigned u = q[t];
    int c = 0;
    #pragma unroll
    for (int h = 0; h < 2; ++h) {
        const unsigned v = (h ? (u >> 16) : u) & 0xFFFFu;
        const unsigned e = (v >> 7) & 0xFFu;
        if (e == 0xFFu || e < 90u || e > 140u) ++c;
    }
    cnt[t] = c;
    __syncthreads();
    if (t == 0) {
        int s = 0;
        for (int i = 0; i < 256; ++i) s += cnt[i];
        *flag = (s > 64) ? 1 : 0;
    }
}

// ---------------------------------------------------------------------------
// Convert key/value/query (3 x 4M) and the 4 W matrices (4 x 1M) to bf16.
// Grid 16384 x 256, 4 elems/thread.
// ---------------------------------------------------------------------------
__global__ __launch_bounds__(256) void cvt_all(
    const void* __restrict__ Akey, const void* __restrict__ Aval, const void* __restrict__ Aqry,
    const void* __restrict__ Wq_, const void* __restrict__ Wk_,
    const void* __restrict__ Wv_, const void* __restrict__ Wo_,
    bf16* __restrict__ bk, bf16* __restrict__ bv, bf16* __restrict__ bq,
    bf16* __restrict__ Wbf, const int* __restrict__ flag)
{
    const int f32 = *flag;
    const unsigned g = blockIdx.x * 256 + threadIdx.x;      // [0, 4M)
    const void* src; bf16* dst; size_t off;
    if (g < (3u << 20)) {
        const int r = g >> 20;                               // 0=key,1=value,2=query
        src = (r == 0) ? Akey : (r == 1) ? Aval : Aqry;
        dst = (r == 0) ? bk   : (r == 1) ? bv   : bq;
        off = (size_t)(g & 0xFFFFFu) * 4;
    } else {
        const unsigned gw = g - (3u << 20);                  // [0, 1M)
        const int r = gw >> 18;                              // 0..3 = Wq,Wk,Wv,Wo
        src = (r == 0) ? Wq_ : (r == 1) ? Wk_ : (r == 2) ? Wv_ : Wo_;
        dst = Wbf + (size_t)r * 1048576;
        off = (size_t)(gw & 0x3FFFFu) * 4;
    }
    short4v sv;
    if (f32) {
        const float4 fa = *(const float4*)((const float*)src + off);
        sv[0] = f2s(fa.x); sv[1] = f2s(fa.y); sv[2] = f2s(fa.z); sv[3] = f2s(fa.w);
    } else {
        const ushort4 ua = *(const ushort4*)((const bf16*)src + off);
        sv[0] = (short)ua.x; sv[1] = (short)ua.y; sv[2] = (short)ua.z; sv[3] = (short)ua.w;
    }
    *(short4v*)(dst + off) = sv;
}

// ---------------------------------------------------------------------------
// MFMA GEMM: all-bf16 operands. 128x128 tile, BK=32, 256 thr (4 waves 2x2).
// XCD-affinity swizzle kept from R6.
// ---------------------------------------------------------------------------
__global__ __launch_bounds__(256) void gemm_mfma(
    const bf16* __restrict__ Aq, const bf16* __restrict__ Ak,
    const bf16* __restrict__ Av, const bf16* __restrict__ Actx,
    const bf16* __restrict__ Wbf,
    const void* __restrict__ Bq_, const void* __restrict__ Bk_,
    const void* __restrict__ Bv_, const void* __restrict__ Bo_,
    bf16* __restrict__ qp, bf16* __restrict__ kp, bf16* __restrict__ vp,
    void* __restrict__ outp, const int* __restrict__ flag, int phase)
{
    __shared__ short As[128*40];
    __shared__ short Bs[128*40];

    const int f32 = *flag;
    const int z = (phase == 0) ? (int)blockIdx.z : 3;
    const bf16 *A; const void *bias;
    float scale = 1.0f;
    if (z == 0)      { A = Aq;   bias = Bq_; scale = 0.125f; }
    else if (z == 1) { A = Ak;   bias = Bk_; }
    else if (z == 2) { A = Av;   bias = Bv_; }
    else             { A = Actx; bias = Bo_; }
    const bf16* W = Wbf + (size_t)z * 1048576;   // z==3 -> Wo slot

    const int t    = threadIdx.x;
    const int ly   = (int)blockIdx.x + 8 * ((int)blockIdx.y & 3);   // m-tile [0,32)
    const int lx   = (int)blockIdx.y >> 2;                          // n-tile [0,8)
    const int m0   = ly * 128, n0 = lx * 128;
    const int wid  = t >> 6, lane = t & 63, quad = lane >> 4, ln = lane & 15;
    const int wm   = (wid >> 1) * 64, wn = (wid & 1) * 64;

    f32x4 acc[4][4];
    const f32x4 zz = {0.f, 0.f, 0.f, 0.f};
    #pragma unroll
    for (int i = 0; i < 4; ++i)
        #pragma unroll
        for (int j = 0; j < 4; ++j) acc[i][j] = zz;

    const int ar = t >> 3, ak4 = t & 7;
    const int bn4 = t & 31, bkq = t >> 5;

    for (int k0 = 0; k0 < D_; k0 += 32) {
        #pragma unroll
        for (int i = 0; i < 4; ++i) {
            const int m = ar + i * 32;
            const ushort4 ua = *(const ushort4*)(A + (size_t)(m0 + m) * D_ + (k0 + ak4 * 4));
            short4v sv; sv[0] = (short)ua.x; sv[1] = (short)ua.y; sv[2] = (short)ua.z; sv[3] = (short)ua.w;
            const int blk = ((ak4 >> 1) ^ ((m >> 2) & 3));
            *(short4v*)(As + m * 40 + blk * 8 + (ak4 & 1) * 4) = sv;
        }
        short tmpw[4][4];
        #pragma unroll
        for (int i = 0; i < 4; ++i) {
            const ushort4 uw = *(const ushort4*)(W + (size_t)(k0 + bkq * 4 + i) * D_ + (n0 + bn4 * 4));
            tmpw[i][0] = (short)uw.x; tmpw[i][1] = (short)uw.y;
            tmpw[i][2] = (short)uw.z; tmpw[i][3] = (short)uw.w;
        }
        #pragma unroll
        for (int c = 0; c < 4; ++c) {
            const int n = bn4 * 4 + c;
            short4v sv;
            sv[0] = tmpw[0][c]; sv[1] = tmpw[1][c];
            sv[2] = tmpw[2][c]; sv[3] = tmpw[3][c];
            const int blk = ((bkq >> 1) ^ ((n >> 2) & 3));
            *(short4v*)(Bs + n * 40 + blk * 8 + (bkq & 1) * 4) = sv;
        }
        __syncthreads();
        short8 af[4], bfv[4];
        #pragma unroll
        for (int mt = 0; mt < 4; ++mt) {
            const int r = wm + mt * 16 + ln;
            const int blk = quad ^ ((r >> 2) & 3);
            af[mt] = *(const short8*)(As + r * 40 + blk * 8);
        }
        #pragma unroll
        for (int nt = 0; nt < 4; ++nt) {
            const int r = wn + nt * 16 + ln;
            const int blk = quad ^ ((r >> 2) & 3);
            bfv[nt] = *(const short8*)(Bs + r * 40 + blk * 8);
        }
        #pragma unroll
        for (int mt = 0; mt < 4; ++mt)
            #pragma unroll
            for (int nt = 0; nt < 4; ++nt)
                acc[mt][nt] = MFMA16(af[mt], bfv[nt], acc[mt][nt]);
        __syncthreads();
    }

    #pragma unroll
    for (int nt = 0; nt < 4; ++nt) {
        const int col = n0 + wn + nt * 16 + ln;
        const float bi = ldin(bias, col, f32);
        const int h = col >> 6, d = col & 63;
        #pragma unroll
        for (int mt = 0; mt < 4; ++mt) {
            #pragma unroll
            for (int reg = 0; reg < 4; ++reg) {
                const int row = m0 + wm + mt * 16 + quad * 4 + reg;
                const float v = (acc[mt][nt][reg] + bi) * scale;
                const int bb = row >> 10, s = row & 1023;
                const size_t hoff = (((size_t)(bb * H_ + h)) * S_ + s) * HD_ + d;
                if (z == 0)      qp[hoff] = f2b(v);
                else if (z == 1) kp[hoff] = f2b(v);
                else if (z == 2) vp[hoff] = f2b(v);
                else             stout(outp, (size_t)row * D_ + col, f32, v);
            }
        }
    }
}

// ---------------------------------------------------------------------------
// Transpose V: vp [b,h,s,d] -> vT [b,h,d,s]   (bf16)  (unchanged)
// ---------------------------------------------------------------------------
__global__ __launch_bounds__(256) void transpose_v(
    const bf16* __restrict__ vp, bf16* __restrict__ vT)
{
    __shared__ short tb[64][68];
    const int t = threadIdx.x;
    const int st = blockIdx.x, h = blockIdx.y, b = blockIdx.z;
    const size_t bh = (size_t)(b * H_ + h) * S_ * HD_;
    const int s0 = st * 64;

    #pragma unroll
    for (int i = 0; i < 4; ++i) {
        const int sl = (t >> 4) + i * 16;
        const int d4 = (t & 15) * 4;
        const ushort4 u = *(const ushort4*)(vp + bh + (size_t)(s0 + sl) * HD_ + d4);
        short4v sv; sv[0] = (short)u.x; sv[1] = (short)u.y; sv[2] = (short)u.z; sv[3] = (short)u.w;
        *(short4v*)(&tb[sl][d4]) = sv;
    }
    __syncthreads();
    #pragma unroll
    for (int i = 0; i < 4; ++i) {
        const int dl = (t >> 4) + i * 16;
        const int s4 = (t & 15) * 4;
        short4v sv;
        sv[0] = tb[s4 + 0][dl]; sv[1] = tb[s4 + 1][dl];
        sv[2] = tb[s4 + 2][dl]; sv[3] = tb[s4 + 3][dl];
        *(short4v*)(vT + bh + (size_t)dl * S_ + s0 + s4) = sv;
    }
}

// ---------------------------------------------------------------------------
// MFMA attention, R14: LDS cut -> 2 blocks/CU co-residency.
//  R13 post-mortem: unroll-1 + relk hoist = 302->228us (I$ confirmed). Grid
//  512 blocks x 92.7KB LDS = 1 block/CU = TWO sequential rounds on 256 CUs.
//  Cutting LDS <=80KB makes both rounds co-resident (16 waves/CU, 4/SIMD at
//  VGPR=108). Unlike R9, co-resident blocks share the same XCD-affine (b,z)
//  K/V stream (id&7), so no L2 drift hazard.
//  Change: Ored[8][16][65] (33.3KB, cross-wave sum via LDS staging) replaced
//  by double-buffered Osum[2][16][65] (8.3KB) accumulated with LDS
//  atomicAdd(f32) (native ds_add). Buffer hh&1 accumulates this head; hh^1
//  is zeroed after barrier R (prev epilogue reads complete; zero->next-adds
//  separated by O1 + next R). LDS 92.2 -> 67.3KB. Epilogue reads 1 value.
//  Everything else identical to R13.
// ---------------------------------------------------------------------------
__global__ __launch_bounds__(512, 1) void attn_mfma(
    const bf16* __restrict__ qp, const bf16* __restrict__ kp, const bf16* __restrict__ vT,
    const void* __restrict__ relk, const void* __restrict__ relv,
    bf16* __restrict__ ctx, bf16* __restrict__ av0, bf16* __restrict__ av1,
    const int* __restrict__ flag)
{
    __shared__ short sc[16][1032];        // 33024 B  unnormalized e (bf16)
    __shared__ float prW[16][65];         //  4160 B  shared pr table
    __shared__ short relvT[64][72];       //  9216 B
    __shared__ short relkL[65][66];       //  8580 B  rel_k bf16 (head-invariant)
    __shared__ short wr[16][72];          //  2304 B  w0 + band taps (unnorm)
    __shared__ float Osum[2][16][65];     //  8320 B  atomic PV accumulators
    __shared__ float rsum[8][16];         //   512 B
    __shared__ float wred[8][16][2];      //  1024 B
    __shared__ float w64sL[16];
    __shared__ float invs[16];

    const int f32 = *flag;
    const int t  = threadIdx.x;           // [0,512)
    const int id = blockIdx.x;
    const int b  = id & 3;                // (b,z) = id & 7 -> XCD affinity
    const int z  = (id >> 2) & 1;
    const int qt = id >> 3;
    const int q0 = qt * 16;
    const int wid = t >> 6, lane = t & 63, quad = lane >> 4, ln = lane & 15;
    const int colbase = wid * 128;        // 8 waves x 128 cols

    // stage relvT + relkL; zero both Osum buffers; zero out-of-range band taps
    for (int i = t; i < 65 * 64; i += 512) relvT[i & 63][i >> 6] = f2s(ldin(relv, i, f32));
    for (int i = t; i < 65 * 64; i += 512) relkL[i >> 6][i & 63] = f2s(ldin(relk, i, f32));
    for (int i = t; i < 2 * 16 * 65; i += 512) ((float*)Osum)[i] = 0.f;
    for (int i = t; i < 16 * 63; i += 512) {
        const int row = i / 63, rel = 1 + i % 63;
        const int col = q0 + row + rel - 32;
        if (col < 0 || col >= S_) wr[row][rel] = 0;
    }
    __syncthreads();

    float av[4][8];
    #pragma unroll
    for (int r = 0; r < 4; ++r)
        #pragma unroll
        for (int c = 0; c < 8; ++c) av[r][c] = 0.f;

    bf16* avout = (z == 0) ? av0 : av1;
    const f32x4 zz = {0.f, 0.f, 0.f, 0.f};

    #pragma unroll 1
    for (int hh = 0; hh < 8; ++hh) {
        const int h = z * 8 + hh;
        const int buf = hh & 1;
        const size_t bhO = (size_t)(b * H_ + h) * S_ * HD_;
        const bf16* qb = qp + bhO;
        const bf16* kb = kp + bhO;
        const bf16* vb = vT + bhO;

        short8 aq[2];
        #pragma unroll
        for (int kt = 0; kt < 2; ++kt)
            aq[kt] = *(const short8*)(qb + (size_t)(q0 + ln) * HD_ + kt * 32 + quad * 8);

        // ---- QK^T over 128 cols: pacc[8], 4-batched loads ----
        f32x4 pacc[8];
        #pragma unroll
        for (int nt = 0; nt < 8; ++nt) pacc[nt] = zz;
        #pragma unroll
        for (int kt = 0; kt < 2; ++kt) {
            #pragma unroll
            for (int half = 0; half < 2; ++half) {
                short8 bkf[4];
                #pragma unroll
                for (int i2 = 0; i2 < 4; ++i2)
                    bkf[i2] = *(const short8*)(kb + (size_t)(colbase + (half * 4 + i2) * 16 + ln) * HD_ + kt * 32 + quad * 8);
                __builtin_amdgcn_s_setprio(1);
                #pragma unroll
                for (int i2 = 0; i2 < 4; ++i2)
                    pacc[half * 4 + i2] = MFMA16(aq[kt], bkf[i2], pacc[half * 4 + i2]);
                __builtin_amdgcn_s_setprio(0);
            }
        }

        // ---- pr = Q @ relk^T from LDS (identical in every wave) ----
        #pragma unroll
        for (int nt = 0; nt < 5; ++nt) {
            const int rel = nt * 16 + ln;
            f32x4 pc = zz;
            #pragma unroll
            for (int kt = 0; kt < 2; ++kt) {
                short8 bb;
                if (rel <= 64) {
                    bb = *(const short8*)(&relkL[rel][kt * 32 + quad * 8]);
                } else {
                    #pragma unroll
                    for (int j = 0; j < 8; ++j) bb[j] = 0;
                }
                pc = MFMA16(aq[kt], bb, pc);
            }
            if (rel <= 64) {
                #pragma unroll
                for (int reg = 0; reg < 4; ++reg) prW[quad * 4 + reg][rel] = pc[reg];
            }
        }
        WAIT_LGKM0();   // own-wave prW writes landed (wave wrote full table)
        __builtin_amdgcn_sched_barrier(0);   // do not hoist prW reads above the drain

        // ---- branchless fixup + exp (no max) + partial sums + sc/band-tap writes ----
        float s4[4] = {0,0,0,0}, w0p[4] = {0,0,0,0}, w64p[4] = {0,0,0,0};
        #pragma unroll
        for (int nt = 0; nt < 8; ++nt) {
            const int col = colbase + nt * 16 + ln;
            float addv[4];
            #pragma unroll
            for (int reg = 0; reg < 4; ++reg) {
                const int row = quad * 4 + reg;
                const int rc = col - (q0 + row) + 32;           // dist + 32
                const int rel_c = rc < 0 ? 0 : (rc > 64 ? 64 : rc);
                addv[reg] = prW[row][rel_c];
            }
            #pragma unroll
            for (int reg = 0; reg < 4; ++reg) {
                const int row = quad * 4 + reg;
                const int rc = col - (q0 + row) + 32;
                const float e = __expf(pacc[nt][reg] + addv[reg]);
                s4[reg] += e;
                if (rc <= 0) w0p[reg] += e;
                else if (rc >= 64) w64p[reg] += e;
                const short es = f2s(e);
                sc[row][col] = es;
                if (rc > 0 && rc < 64) wr[row][rc] = es;
            }
        }
        #pragma unroll
        for (int off = 1; off < 16; off <<= 1) {
            #pragma unroll
            for (int reg = 0; reg < 4; ++reg) {
                s4[reg]  += __shfl_xor(s4[reg],  off, 16);
                w0p[reg] += __shfl_xor(w0p[reg], off, 16);
                w64p[reg]+= __shfl_xor(w64p[reg],off, 16);
            }
        }
        if (ln == 0) {
            #pragma unroll
            for (int reg = 0; reg < 4; ++reg) {
                const int row = quad * 4 + reg;
                rsum[wid][row] = s4[reg];
                wred[wid][row][0] = w0p[reg];
                wred[wid][row][1] = w64p[reg];
            }
        }
        __syncthreads();   // ===== R: sc/wr/rsum/wred ready; prev epilogue done =====

        // zero the OTHER Osum buffer for the next head (safe: prev reads done)
        for (int i = t; i < 16 * 65; i += 512) ((float*)Osum[buf ^ 1])[i] = 0.f;

        float inv[4];
        #pragma unroll
        for (int reg = 0; reg < 4; ++reg) {
            const int row = quad * 4 + reg;
            float s = 0.f;
            #pragma unroll
            for (int w = 0; w < 8; ++w) s += rsum[w][row];
            inv[reg] = 1.0f / s;
        }
        if (wid == 1 && ln == 0) {
            #pragma unroll
            for (int reg = 0; reg < 4; ++reg) invs[quad * 4 + reg] = inv[reg];
        }
        if (wid == 0 && ln == 0) {
            #pragma unroll
            for (int reg = 0; reg < 4; ++reg) {
                const int row = quad * 4 + reg;
                float w0u = 0.f, w64u = 0.f;
                #pragma unroll
                for (int w = 0; w < 8; ++w) { w0u += wred[w][row][0]; w64u += wred[w][row][1]; }
                wr[row][0] = f2s(w0u);
                w64sL[row] = w64u;
            }
        }

        // ---- PV over 128 cols (4 k-steps) + wave0 extended rel_v chunks ----
        f32x4 oacc[4];
        #pragma unroll
        for (int dt = 0; dt < 4; ++dt) oacc[dt] = zz;
        #pragma unroll
        for (int kp2 = 0; kp2 < 2; ++kp2) {
            short8 ap[2]; short8 bv[8];
            #pragma unroll
            for (int k2 = 0; k2 < 2; ++k2) {
                const int kt = kp2 * 2 + k2;
                ap[k2] = *(const short8*)(&sc[ln][colbase + kt * 32 + quad * 8]);
                #pragma unroll
                for (int dt = 0; dt < 4; ++dt)
                    bv[k2 * 4 + dt] = *(const short8*)(vb + (size_t)(dt * 16 + ln) * S_ + colbase + kt * 32 + quad * 8);
            }
            __builtin_amdgcn_s_setprio(1);
            #pragma unroll
            for (int k2 = 0; k2 < 2; ++k2)
                #pragma unroll
                for (int dt = 0; dt < 4; ++dt)
                    oacc[dt] = MFMA16(ap[k2], bv[k2 * 4 + dt], oacc[dt]);
            __builtin_amdgcn_s_setprio(0);
        }

        // ---- av accumulate from sc (bf16 e, one short8 per row) ----
        #pragma unroll
        for (int reg = 0; reg < 4; ++reg) {
            const int row = quad * 4 + reg;
            const short8 e0 = *(const short8*)(&sc[row][colbase + ln * 8]);
            #pragma unroll
            for (int j = 0; j < 8; ++j)
                av[reg][j] += s2f(e0[j]) * inv[reg];
        }

        if (wid == 0) {
            WAIT_LGKM0();   // wr[row][0] write (own wave) landed
            #pragma unroll
            for (int kt = 0; kt < 2; ++kt) {
                const short8 aw = *(const short8*)(&wr[ln][kt * 32 + quad * 8]);
                #pragma unroll
                for (int dt = 0; dt < 4; ++dt) {
                    const short8 br = *(const short8*)(&relvT[dt * 16 + ln][kt * 32 + quad * 8]);
                    oacc[dt] = MFMA16(aw, br, oacc[dt]);
                }
            }
        }
        // cross-wave PV reduction via LDS float atomics (distinct cells per lane)
        #pragma unroll
        for (int dt = 0; dt < 4; ++dt)
            #pragma unroll
            for (int reg = 0; reg < 4; ++reg)
                atomicAdd(&Osum[buf][quad * 4 + reg][dt * 16 + ln], oacc[dt][reg]);
        __syncthreads();   // ===== O1: Osum/invs/w64sL ready =====

        #pragma unroll
        for (int i = 0; i < 2; ++i) {
            const int c = t + i * 512;
            const int row = c >> 6, d = c & 63;
            const float o = Osum[buf][row][d] + w64sL[row] * s2f(relvT[d][64]);
            ctx[((size_t)(b * S_ + q0 + row)) * D_ + h * HD_ + d] = f2b(o * invs[row]);
        }
    }

    // ---- final av store: 8 contiguous bf16 per row per thread ----
    #pragma unroll
    for (int reg = 0; reg < 4; ++reg) {
        const int row = quad * 4 + reg;
        short8 s0;
        #pragma unroll
        for (int j = 0; j < 8; ++j) s0[j] = f2s(av[reg][j]);
        const size_t base = ((size_t)(b * S_ + q0 + row)) * S_ + colbase + ln * 8;
        *(short8*)(avout + base) = s0;
    }
}

// ---------------------------------------------------------------------------
__global__ __launch_bounds__(256) void combine_av(
    const bf16* __restrict__ a, const bf16* __restrict__ bsrc,
    void* __restrict__ dout, const int* __restrict__ flag)
{
    const int f32 = *flag;
    const size_t i4 = ((size_t)blockIdx.x * 256 + threadIdx.x) * 4;
    const ushort4 x = *(const ushort4*)(a + i4);
    const ushort4 y = *(const ushort4*)(bsrc + i4);
    stout(dout, OUT0_ + i4 + 0, f32, (s2f((short)x.x) + s2f((short)y.x)) * 0.0625f);
    stout(dout, OUT0_ + i4 + 1, f32, (s2f((short)x.y) + s2f((short)y.y)) * 0.0625f);
    stout(dout, OUT0_ + i4 + 2, f32, (s2f((short)x.z) + s2f((short)y.z)) * 0.0625f);
    stout(dout, OUT0_ + i4 + 3, f32, (s2f((short)x.w) + s2f((short)y.w)) * 0.0625f);
}

// ---------------------------------------------------------------------------
extern "C" void kernel_launch(void* const* d_in, const int* in_sizes, int n_in,
                              void* d_out, int out_size, void* d_ws, size_t ws_size,
                              hipStream_t stream)
{
    char* w    = (char*)d_ws;                     // 64 MB + 4 B
    bf16*  qp  = (bf16*)(w);                      //  0..8
    bf16*  kp  = (bf16*)(w + (8ull  << 20));      //  8..16
    bf16*  vT  = (bf16*)(w + (16ull << 20));      // 16..24
    bf16*  ctx = (bf16*)(w + (24ull << 20));      // 24..32  (= key-bf16 during p0)
    bf16*  vp  = (bf16*)(w + (32ull << 20));      // 32..40  (dead after transpose)
    bf16*  av0 = (bf16*)(w + (40ull << 20));      // 40..48  (= value-bf16 during p0)
    bf16*  av1 = (bf16*)(w + (48ull << 20));      // 48..56  (= query-bf16 during p0)
    bf16*  Wbf = (bf16*)(w + (56ull << 20));      // 56..64
    int*  flag = (int*)  (w + (64ull << 20));

    bf16* Abf_k = ctx;       // key bf16   (overwritten later by attn ctx)
    bf16* Abf_v = av0;       // value bf16 (overwritten later by attn av0)
    bf16* Abf_q = av1;       // query bf16 (overwritten later by attn av1)

    hipLaunchKernelGGL(dtype_probe, dim3(1), dim3(256), 0, stream,
                       (const unsigned int*)d_in[2], flag);
    hipLaunchKernelGGL(cvt_all, dim3(16384), dim3(256), 0, stream,
                       d_in[0], d_in[1], d_in[2],
                       d_in[4], d_in[6], d_in[8], d_in[10],
                       Abf_k, Abf_v, Abf_q, Wbf, (const int*)flag);
    hipLaunchKernelGGL(gemm_mfma, dim3(8, 32, 3), dim3(256), 0, stream,
                       (const bf16*)Abf_q, (const bf16*)Abf_k, (const bf16*)Abf_v, (const bf16*)ctx,
                       (const bf16*)Wbf, d_in[5], d_in[7], d_in[9], d_in[11],
                       qp, kp, vp, d_out, (const int*)flag, 0);
    hipLaunchKernelGGL(transpose_v, dim3(16, 16, 4), dim3(256), 0, stream,
                       (const bf16*)vp, vT);
    hipLaunchKernelGGL(attn_mfma, dim3(512), dim3(512), 0, stream,
                       (const bf16*)qp, (const bf16*)kp, (const bf16*)vT,
                       d_in[12], d_in[13], ctx, av0, av1, (const int*)flag);
    hipLaunchKernelGGL(combine_av, dim3(4096), dim3(256), 0, stream,
                       (const bf16*)av0, (const bf16*)av1, d_out, (const int*)flag);
    hipLaunchKernelGGL(gemm_mfma, dim3(8, 32, 1), dim3(256), 0, stream,
                       (const bf16*)Abf_q, (const bf16*)Abf_k, (const bf16*)Abf_v, (const bf16*)ctx,
                       (const bf16*)Wbf, d_in[5], d_in[7], d_in[9], d_in[11],
                       qp, kp, vp, d_out, (const int*)flag, 1);
}

// Round 10
// 440.075 us; speedup vs baseline: 1.4235x; 1.4235x over previous
//
#include <hip/hip_runtime.h>
#include <hip/hip_bf16.h>

#define B_ 4
#define S_ 1024
#define D_ 1024
#define H_ 16
#define HD_ 64
#define OUT0_ 4194304ull   // B*S*D

typedef __hip_bfloat16 bf16;
typedef __attribute__((ext_vector_type(8))) short short8;
typedef __attribute__((ext_vector_type(4))) short short4v;
typedef __attribute__((ext_vector_type(4))) float f32x4;

#define MFMA16(a,b,c) __builtin_amdgcn_mfma_f32_16x16x32_bf16(a,b,c,0,0,0)
#define WAIT_LGKM0() __builtin_amdgcn_s_waitcnt(0xC07F)   // lgkmcnt(0), vm/exp unconstrained

__device__ __forceinline__ float b2f(bf16 x){ return __bfloat162float(x); }
__device__ __forceinline__ bf16  f2b(float x){ return __float2bfloat16(x); }
__device__ __forceinline__ short f2s(float x){ bf16 h = __float2bfloat16(x); return *reinterpret_cast<short*>(&h); }
__device__ __forceinline__ float s2f(short u){ return __uint_as_float(((unsigned)(unsigned short)u) << 16); }
__device__ __forceinline__ float ldin(const void* p, size_t i, int f32){
    return f32 ? ((const float*)p)[i] : b2f(((const bf16*)p)[i]);
}
__device__ __forceinline__ void stout(void* p, size_t i, int f32, float v){
    if (f32) ((float*)p)[i] = v; else ((bf16*)p)[i] = f2b(v);
}

// ---------------------------------------------------------------------------
// dtype probe (kept: established fp32 on this dataset, cheap and safe)
// ---------------------------------------------------------------------------
__global__ void dtype_probe(const unsigned int* __restrict__ q, int* __restrict__ flag)
{
    __shared__ int cnt[256];
    const int t = threadIdx.x;
    const unsigned u = q[t];
    int c = 0;
    #pragma unroll
    for (int h = 0; h < 2; ++h) {
        const unsigned v = (h ? (u >> 16) : u) & 0xFFFFu;
        const unsigned e = (v >> 7) & 0xFFu;
        if (e == 0xFFu || e < 90u || e > 140u) ++c;
    }
    cnt[t] = c;
    __syncthreads();
    if (t == 0) {
        int s = 0;
        for (int i = 0; i < 256; ++i) s += cnt[i];
        *flag = (s > 64) ? 1 : 0;
    }
}

// ---------------------------------------------------------------------------
// Convert key/value/query (3 x 4M) and the 4 W matrices (4 x 1M) to bf16.
// Grid 16384 x 256, 4 elems/thread.
// ---------------------------------------------------------------------------
__global__ __launch_bounds__(256) void cvt_all(
    const void* __restrict__ Akey, const void* __restrict__ Aval, const void* __restrict__ Aqry,
    const void* __restrict__ Wq_, const void* __restrict__ Wk_,
    const void* __restrict__ Wv_, const void* __restrict__ Wo_,
    bf16* __restrict__ bk, bf16* __restrict__ bv, bf16* __restrict__ bq,
    bf16* __restrict__ Wbf, const int* __restrict__ flag)
{
    const int f32 = *flag;
    const unsigned g = blockIdx.x * 256 + threadIdx.x;      // [0, 4M)
    const void* src; bf16* dst; size_t off;
    if (g < (3u << 20)) {
        const int r = g >> 20;                               // 0=key,1=value,2=query
        src = (r == 0) ? Akey : (r == 1) ? Aval : Aqry;
        dst = (r == 0) ? bk   : (r == 1) ? bv   : bq;
        off = (size_t)(g & 0xFFFFFu) * 4;
    } else {
        const unsigned gw = g - (3u << 20);                  // [0, 1M)
        const int r = gw >> 18;                              // 0..3 = Wq,Wk,Wv,Wo
        src = (r == 0) ? Wq_ : (r == 1) ? Wk_ : (r == 2) ? Wv_ : Wo_;
        dst = Wbf + (size_t)r * 1048576;
        off = (size_t)(gw & 0x3FFFFu) * 4;
    }
    short4v sv;
    if (f32) {
        const float4 fa = *(const float4*)((const float*)src + off);
        sv[0] = f2s(fa.x); sv[1] = f2s(fa.y); sv[2] = f2s(fa.z); sv[3] = f2s(fa.w);
    } else {
        const ushort4 ua = *(const ushort4*)((const bf16*)src + off);
        sv[0] = (short)ua.x; sv[1] = (short)ua.y; sv[2] = (short)ua.z; sv[3] = (short)ua.w;
    }
    *(short4v*)(dst + off) = sv;
}

// ---------------------------------------------------------------------------
// MFMA GEMM: all-bf16 operands. 128x128 tile, BK=32, 256 thr (4 waves 2x2).
// XCD-affinity swizzle kept from R6.
// ---------------------------------------------------------------------------
__global__ __launch_bounds__(256) void gemm_mfma(
    const bf16* __restrict__ Aq, const bf16* __restrict__ Ak,
    const bf16* __restrict__ Av, const bf16* __restrict__ Actx,
    const bf16* __restrict__ Wbf,
    const void* __restrict__ Bq_, const void* __restrict__ Bk_,
    const void* __restrict__ Bv_, const void* __restrict__ Bo_,
    bf16* __restrict__ qp, bf16* __restrict__ kp, bf16* __restrict__ vp,
    void* __restrict__ outp, const int* __restrict__ flag, int phase)
{
    __shared__ short As[128*40];
    __shared__ short Bs[128*40];

    const int f32 = *flag;
    const int z = (phase == 0) ? (int)blockIdx.z : 3;
    const bf16 *A; const void *bias;
    float scale = 1.0f;
    if (z == 0)      { A = Aq;   bias = Bq_; scale = 0.125f; }
    else if (z == 1) { A = Ak;   bias = Bk_; }
    else if (z == 2) { A = Av;   bias = Bv_; }
    else             { A = Actx; bias = Bo_; }
    const bf16* W = Wbf + (size_t)z * 1048576;   // z==3 -> Wo slot

    const int t    = threadIdx.x;
    const int ly   = (int)blockIdx.x + 8 * ((int)blockIdx.y & 3);   // m-tile [0,32)
    const int lx   = (int)blockIdx.y >> 2;                          // n-tile [0,8)
    const int m0   = ly * 128, n0 = lx * 128;
    const int wid  = t >> 6, lane = t & 63, quad = lane >> 4, ln = lane & 15;
    const int wm   = (wid >> 1) * 64, wn = (wid & 1) * 64;

    f32x4 acc[4][4];
    const f32x4 zz = {0.f, 0.f, 0.f, 0.f};
    #pragma unroll
    for (int i = 0; i < 4; ++i)
        #pragma unroll
        for (int j = 0; j < 4; ++j) acc[i][j] = zz;

    const int ar = t >> 3, ak4 = t & 7;
    const int bn4 = t & 31, bkq = t >> 5;

    for (int k0 = 0; k0 < D_; k0 += 32) {
        #pragma unroll
        for (int i = 0; i < 4; ++i) {
            const int m = ar + i * 32;
            const ushort4 ua = *(const ushort4*)(A + (size_t)(m0 + m) * D_ + (k0 + ak4 * 4));
            short4v sv; sv[0] = (short)ua.x; sv[1] = (short)ua.y; sv[2] = (short)ua.z; sv[3] = (short)ua.w;
            const int blk = ((ak4 >> 1) ^ ((m >> 2) & 3));
            *(short4v*)(As + m * 40 + blk * 8 + (ak4 & 1) * 4) = sv;
        }
        short tmpw[4][4];
        #pragma unroll
        for (int i = 0; i < 4; ++i) {
            const ushort4 uw = *(const ushort4*)(W + (size_t)(k0 + bkq * 4 + i) * D_ + (n0 + bn4 * 4));
            tmpw[i][0] = (short)uw.x; tmpw[i][1] = (short)uw.y;
            tmpw[i][2] = (short)uw.z; tmpw[i][3] = (short)uw.w;
        }
        #pragma unroll
        for (int c = 0; c < 4; ++c) {
            const int n = bn4 * 4 + c;
            short4v sv;
            sv[0] = tmpw[0][c]; sv[1] = tmpw[1][c];
            sv[2] = tmpw[2][c]; sv[3] = tmpw[3][c];
            const int blk = ((bkq >> 1) ^ ((n >> 2) & 3));
            *(short4v*)(Bs + n * 40 + blk * 8 + (bkq & 1) * 4) = sv;
        }
        __syncthreads();
        short8 af[4], bfv[4];
        #pragma unroll
        for (int mt = 0; mt < 4; ++mt) {
            const int r = wm + mt * 16 + ln;
            const int blk = quad ^ ((r >> 2) & 3);
            af[mt] = *(const short8*)(As + r * 40 + blk * 8);
        }
        #pragma unroll
        for (int nt = 0; nt < 4; ++nt) {
            const int r = wn + nt * 16 + ln;
            const int blk = quad ^ ((r >> 2) & 3);
            bfv[nt] = *(const short8*)(Bs + r * 40 + blk * 8);
        }
        #pragma unroll
        for (int mt = 0; mt < 4; ++mt)
            #pragma unroll
            for (int nt = 0; nt < 4; ++nt)
                acc[mt][nt] = MFMA16(af[mt], bfv[nt], acc[mt][nt]);
        __syncthreads();
    }

    #pragma unroll
    for (int nt = 0; nt < 4; ++nt) {
        const int col = n0 + wn + nt * 16 + ln;
        const float bi = ldin(bias, col, f32);
        const int h = col >> 6, d = col & 63;
        #pragma unroll
        for (int mt = 0; mt < 4; ++mt) {
            #pragma unroll
            for (int reg = 0; reg < 4; ++reg) {
                const int row = m0 + wm + mt * 16 + quad * 4 + reg;
                const float v = (acc[mt][nt][reg] + bi) * scale;
                const int bb = row >> 10, s = row & 1023;
                const size_t hoff = (((size_t)(bb * H_ + h)) * S_ + s) * HD_ + d;
                if (z == 0)      qp[hoff] = f2b(v);
                else if (z == 1) kp[hoff] = f2b(v);
                else if (z == 2) vp[hoff] = f2b(v);
                else             stout(outp, (size_t)row * D_ + col, f32, v);
            }
        }
    }
}

// ---------------------------------------------------------------------------
// Transpose V: vp [b,h,s,d] -> vT [b,h,d,s]   (bf16)  (unchanged)
// ---------------------------------------------------------------------------
__global__ __launch_bounds__(256) void transpose_v(
    const bf16* __restrict__ vp, bf16* __restrict__ vT)
{
    __shared__ short tb[64][68];
    const int t = threadIdx.x;
    const int st = blockIdx.x, h = blockIdx.y, b = blockIdx.z;
    const size_t bh = (size_t)(b * H_ + h) * S_ * HD_;
    const int s0 = st * 64;

    #pragma unroll
    for (int i = 0; i < 4; ++i) {
        const int sl = (t >> 4) + i * 16;
        const int d4 = (t & 15) * 4;
        const ushort4 u = *(const ushort4*)(vp + bh + (size_t)(s0 + sl) * HD_ + d4);
        short4v sv; sv[0] = (short)u.x; sv[1] = (short)u.y; sv[2] = (short)u.z; sv[3] = (short)u.w;
        *(short4v*)(&tb[sl][d4]) = sv;
    }
    __syncthreads();
    #pragma unroll
    for (int i = 0; i < 4; ++i) {
        const int dl = (t >> 4) + i * 16;
        const int s4 = (t & 15) * 4;
        short4v sv;
        sv[0] = tb[s4 + 0][dl]; sv[1] = tb[s4 + 1][dl];
        sv[2] = tb[s4 + 2][dl]; sv[3] = tb[s4 + 3][dl];
        *(short4v*)(vT + bh + (size_t)dl * S_ + s0 + s4) = sv;
    }
}

// ---------------------------------------------------------------------------
// MFMA attention, R15 (re-run; R9 bench was an infra failure — same signature
// as R2/R3, where the identical kernel passed on re-run; audit found no
// kernel-attributable failure mode: no OOB, no divergent barriers, liveness
// ~150-180 regs, same ordering discipline as the passing R13).
//  R14 post-mortem: LDS atomicAdd reduction cost +150us (8-wave serialization
//  on ds_add round-trips) and co-residency did NOT materialize anyway. Back
//  to Ored staging (R13 = 228us baseline).
//  New vs R13: two latency windows removed -
//   (1) all 16 K-fragment loads issued up front, then 16 QK MFMAs (one
//       exposed-latency window instead of 4 partially-hidden ones);
//   (2) all 16 V loads hoisted to BEFORE the softmax shuffle/barrier R -
//       their ~500+cy latency hides under shuffle tree + barrier + inv,
//       instead of stalling PV after barrier R.
//  Kept from R13: unroll-1 head loop (I$-resident), relkL staged in LDS,
//  branchless clamped-prW exp, av re-read from sc, 8 waves x 128 cols.
// ---------------------------------------------------------------------------
__global__ __launch_bounds__(512, 1) void attn_mfma(
    const bf16* __restrict__ qp, const bf16* __restrict__ kp, const bf16* __restrict__ vT,
    const void* __restrict__ relk, const void* __restrict__ relv,
    bf16* __restrict__ ctx, bf16* __restrict__ av0, bf16* __restrict__ av1,
    const int* __restrict__ flag)
{
    __shared__ short sc[16][1032];        // 33024 B  unnormalized e (bf16)
    __shared__ float prW[16][65];         //  4160 B  shared pr table
    __shared__ short relvT[64][72];       //  9216 B
    __shared__ short relkL[65][66];       //  8580 B  rel_k bf16 (head-invariant)
    __shared__ short wr[16][72];          //  2304 B  w0 + band taps (unnorm)
    __shared__ float Ored[8][16][65];     // 33280 B
    __shared__ float rsum[8][16];         //   512 B
    __shared__ float wred[8][16][2];      //  1024 B
    __shared__ float w64sL[16];
    __shared__ float invs[16];

    const int f32 = *flag;
    const int t  = threadIdx.x;           // [0,512)
    const int id = blockIdx.x;
    const int b  = id & 3;                // (b,z) = id & 7 -> XCD affinity
    const int z  = (id >> 2) & 1;
    const int qt = id >> 3;
    const int q0 = qt * 16;
    const int wid = t >> 6, lane = t & 63, quad = lane >> 4, ln = lane & 15;
    const int colbase = wid * 128;        // 8 waves x 128 cols

    // stage relvT + relkL; zero out-of-range band taps (q0-invariant)
    for (int i = t; i < 65 * 64; i += 512) relvT[i & 63][i >> 6] = f2s(ldin(relv, i, f32));
    for (int i = t; i < 65 * 64; i += 512) relkL[i >> 6][i & 63] = f2s(ldin(relk, i, f32));
    for (int i = t; i < 16 * 63; i += 512) {
        const int row = i / 63, rel = 1 + i % 63;
        const int col = q0 + row + rel - 32;
        if (col < 0 || col >= S_) wr[row][rel] = 0;
    }
    __syncthreads();

    float av[4][8];
    #pragma unroll
    for (int r = 0; r < 4; ++r)
        #pragma unroll
        for (int c = 0; c < 8; ++c) av[r][c] = 0.f;

    bf16* avout = (z == 0) ? av0 : av1;
    const f32x4 zz = {0.f, 0.f, 0.f, 0.f};

    #pragma unroll 1
    for (int hh = 0; hh < 8; ++hh) {
        const int h = z * 8 + hh;
        const size_t bhO = (size_t)(b * H_ + h) * S_ * HD_;
        const bf16* qb = qp + bhO;
        const bf16* kb = kp + bhO;
        const bf16* vb = vT + bhO;

        short8 aq[2];
        #pragma unroll
        for (int kt = 0; kt < 2; ++kt)
            aq[kt] = *(const short8*)(qb + (size_t)(q0 + ln) * HD_ + kt * 32 + quad * 8);

        // ---- QK^T over 128 cols: issue ALL 16 K loads, then 16 MFMAs ----
        f32x4 pacc[8];
        #pragma unroll
        for (int nt = 0; nt < 8; ++nt) pacc[nt] = zz;
        short8 bkf[16];
        #pragma unroll
        for (int kt = 0; kt < 2; ++kt)
            #pragma unroll
            for (int i2 = 0; i2 < 8; ++i2)
                bkf[kt * 8 + i2] = *(const short8*)(kb + (size_t)(colbase + i2 * 16 + ln) * HD_ + kt * 32 + quad * 8);
        __builtin_amdgcn_s_setprio(1);
        #pragma unroll
        for (int kt = 0; kt < 2; ++kt)
            #pragma unroll
            for (int i2 = 0; i2 < 8; ++i2)
                pacc[i2] = MFMA16(aq[kt], bkf[kt * 8 + i2], pacc[i2]);
        __builtin_amdgcn_s_setprio(0);

        // ---- pr = Q @ relk^T from LDS (identical in every wave) ----
        #pragma unroll
        for (int nt = 0; nt < 5; ++nt) {
            const int rel = nt * 16 + ln;
            f32x4 pc = zz;
            #pragma unroll
            for (int kt = 0; kt < 2; ++kt) {
                short8 bb;
                if (rel <= 64) {
                    bb = *(const short8*)(&relkL[rel][kt * 32 + quad * 8]);
                } else {
                    #pragma unroll
                    for (int j = 0; j < 8; ++j) bb[j] = 0;
                }
                pc = MFMA16(aq[kt], bb, pc);
            }
            if (rel <= 64) {
                #pragma unroll
                for (int reg = 0; reg < 4; ++reg) prW[quad * 4 + reg][rel] = pc[reg];
            }
        }
        WAIT_LGKM0();   // own-wave prW writes landed (wave wrote full table)
        __builtin_amdgcn_sched_barrier(0);   // do not hoist prW reads above the drain

        // ---- branchless fixup + exp (no max) + partial sums + sc/band-tap writes ----
        float s4[4] = {0,0,0,0}, w0p[4] = {0,0,0,0}, w64p[4] = {0,0,0,0};
        #pragma unroll
        for (int nt = 0; nt < 8; ++nt) {
            const int col = colbase + nt * 16 + ln;
            float addv[4];
            #pragma unroll
            for (int reg = 0; reg < 4; ++reg) {
                const int row = quad * 4 + reg;
                const int rc = col - (q0 + row) + 32;           // dist + 32
                const int rel_c = rc < 0 ? 0 : (rc > 64 ? 64 : rc);
                addv[reg] = prW[row][rel_c];
            }
            #pragma unroll
            for (int reg = 0; reg < 4; ++reg) {
                const int row = quad * 4 + reg;
                const int rc = col - (q0 + row) + 32;
                const float e = __expf(pacc[nt][reg] + addv[reg]);
                s4[reg] += e;
                if (rc <= 0) w0p[reg] += e;
                else if (rc >= 64) w64p[reg] += e;
                const short es = f2s(e);
                sc[row][col] = es;
                if (rc > 0 && rc < 64) wr[row][rc] = es;
            }
        }

        // ---- hoisted V loads: latency hides under shuffles + barrier R + inv ----
        short8 bv[16];
        #pragma unroll
        for (int kt = 0; kt < 4; ++kt)
            #pragma unroll
            for (int dt = 0; dt < 4; ++dt)
                bv[kt * 4 + dt] = *(const short8*)(vb + (size_t)(dt * 16 + ln) * S_ + colbase + kt * 32 + quad * 8);

        #pragma unroll
        for (int off = 1; off < 16; off <<= 1) {
            #pragma unroll
            for (int reg = 0; reg < 4; ++reg) {
                s4[reg]  += __shfl_xor(s4[reg],  off, 16);
                w0p[reg] += __shfl_xor(w0p[reg], off, 16);
                w64p[reg]+= __shfl_xor(w64p[reg],off, 16);
            }
        }
        if (ln == 0) {
            #pragma unroll
            for (int reg = 0; reg < 4; ++reg) {
                const int row = quad * 4 + reg;
                rsum[wid][row] = s4[reg];
                wred[wid][row][0] = w0p[reg];
                wred[wid][row][1] = w64p[reg];
            }
        }
        __syncthreads();   // ===== R: sc/wr/rsum/wred ready =====

        float inv[4];
        #pragma unroll
        for (int reg = 0; reg < 4; ++reg) {
            const int row = quad * 4 + reg;
            float s = 0.f;
            #pragma unroll
            for (int w = 0; w < 8; ++w) s += rsum[w][row];
            inv[reg] = 1.0f / s;
        }
        if (wid == 1 && ln == 0) {
            #pragma unroll
            for (int reg = 0; reg < 4; ++reg) invs[quad * 4 + reg] = inv[reg];
        }
        if (wid == 0 && ln == 0) {
            #pragma unroll
            for (int reg = 0; reg < 4; ++reg) {
                const int row = quad * 4 + reg;
                float w0u = 0.f, w64u = 0.f;
                #pragma unroll
                for (int w = 0; w < 8; ++w) { w0u += wred[w][row][0]; w64u += wred[w][row][1]; }
                wr[row][0] = f2s(w0u);
                w64sL[row] = w64u;
            }
        }

        // ---- PV over 128 cols: ap from sc (post-R), bv already in regs ----
        f32x4 oacc[4];
        #pragma unroll
        for (int dt = 0; dt < 4; ++dt) oacc[dt] = zz;
        short8 ap[4];
        #pragma unroll
        for (int kt = 0; kt < 4; ++kt)
            ap[kt] = *(const short8*)(&sc[ln][colbase + kt * 32 + quad * 8]);
        __builtin_amdgcn_s_setprio(1);
        #pragma unroll
        for (int kt = 0; kt < 4; ++kt)
            #pragma unroll
            for (int dt = 0; dt < 4; ++dt)
                oacc[dt] = MFMA16(ap[kt], bv[kt * 4 + dt], oacc[dt]);
        __builtin_amdgcn_s_setprio(0);

        // ---- av accumulate from sc (bf16 e, one short8 per row) ----
        #pragma unroll
        for (int reg = 0; reg < 4; ++reg) {
            const int row = quad * 4 + reg;
            const short8 e0 = *(const short8*)(&sc[row][colbase + ln * 8]);
            #pragma unroll
            for (int j = 0; j < 8; ++j)
                av[reg][j] += s2f(e0[j]) * inv[reg];
        }

        if (wid == 0) {
            WAIT_LGKM0();   // wr[row][0] write (own wave) landed
            #pragma unroll
            for (int kt = 0; kt < 2; ++kt) {
                const short8 aw = *(const short8*)(&wr[ln][kt * 32 + quad * 8]);
                #pragma unroll
                for (int dt = 0; dt < 4; ++dt) {
                    const short8 br = *(const short8*)(&relvT[dt * 16 + ln][kt * 32 + quad * 8]);
                    oacc[dt] = MFMA16(aw, br, oacc[dt]);
                }
            }
        }
        #pragma unroll
        for (int dt = 0; dt < 4; ++dt)
            #pragma unroll
            for (int reg = 0; reg < 4; ++reg)
                Ored[wid][quad * 4 + reg][dt * 16 + ln] = oacc[dt][reg];
        __syncthreads();   // ===== O1: Ored/invs/w64sL ready =====

        #pragma unroll
        for (int i = 0; i < 2; ++i) {
            const int c = t + i * 512;
            const int row = c >> 6, d = c & 63;
            float o = w64sL[row] * s2f(relvT[d][64]);
            #pragma unroll
            for (int w = 0; w < 8; ++w) o += Ored[w][row][d];
            ctx[((size_t)(b * S_ + q0 + row)) * D_ + h * HD_ + d] = f2b(o * invs[row]);
        }
    }

    // ---- final av store: 8 contiguous bf16 per row per thread ----
    #pragma unroll
    for (int reg = 0; reg < 4; ++reg) {
        const int row = quad * 4 + reg;
        short8 s0;
        #pragma unroll
        for (int j = 0; j < 8; ++j) s0[j] = f2s(av[reg][j]);
        const size_t base = ((size_t)(b * S_ + q0 + row)) * S_ + colbase + ln * 8;
        *(short8*)(avout + base) = s0;
    }
}

// ---------------------------------------------------------------------------
__global__ __launch_bounds__(256) void combine_av(
    const bf16* __restrict__ a, const bf16* __restrict__ bsrc,
    void* __restrict__ dout, const int* __restrict__ flag)
{
    const int f32 = *flag;
    const size_t i4 = ((size_t)blockIdx.x * 256 + threadIdx.x) * 4;
    const ushort4 x = *(const ushort4*)(a + i4);
    const ushort4 y = *(const ushort4*)(bsrc + i4);
    stout(dout, OUT0_ + i4 + 0, f32, (s2f((short)x.x) + s2f((short)y.x)) * 0.0625f);
    stout(dout, OUT0_ + i4 + 1, f32, (s2f((short)x.y) + s2f((short)y.y)) * 0.0625f);
    stout(dout, OUT0_ + i4 + 2, f32, (s2f((short)x.z) + s2f((short)y.z)) * 0.0625f);
    stout(dout, OUT0_ + i4 + 3, f32, (s2f((short)x.w) + s2f((short)y.w)) * 0.0625f);
}

// ---------------------------------------------------------------------------
extern "C" void kernel_launch(void* const* d_in, const int* in_sizes, int n_in,
                              void* d_out, int out_size, void* d_ws, size_t ws_size,
                              hipStream_t stream)
{
    char* w    = (char*)d_ws;                     // 64 MB + 4 B
    bf16*  qp  = (bf16*)(w);                      //  0..8
    bf16*  kp  = (bf16*)(w + (8ull  << 20));      //  8..16
    bf16*  vT  = (bf16*)(w + (16ull << 20));      // 16..24
    bf16*  ctx = (bf16*)(w + (24ull << 20));      // 24..32  (= key-bf16 during p0)
    bf16*  vp  = (bf16*)(w + (32ull << 20));      // 32..40  (dead after transpose)
    bf16*  av0 = (bf16*)(w + (40ull << 20));      // 40..48  (= value-bf16 during p0)
    bf16*  av1 = (bf16*)(w + (48ull << 20));      // 48..56  (= query-bf16 during p0)
    bf16*  Wbf = (bf16*)(w + (56ull << 20));      // 56..64
    int*  flag = (int*)  (w + (64ull << 20));

    bf16* Abf_k = ctx;       // key bf16   (overwritten later by attn ctx)
    bf16* Abf_v = av0;       // value bf16 (overwritten later by attn av0)
    bf16* Abf_q = av1;       // query bf16 (overwritten later by attn av1)

    hipLaunchKernelGGL(dtype_probe, dim3(1), dim3(256), 0, stream,
                       (const unsigned int*)d_in[2], flag);
    hipLaunchKernelGGL(cvt_all, dim3(16384), dim3(256), 0, stream,
                       d_in[0], d_in[1], d_in[2],
                       d_in[4], d_in[6], d_in[8], d_in[10],
                       Abf_k, Abf_v, Abf_q, Wbf, (const int*)flag);
    hipLaunchKernelGGL(gemm_mfma, dim3(8, 32, 3), dim3(256), 0, stream,
                       (const bf16*)Abf_q, (const bf16*)Abf_k, (const bf16*)Abf_v, (const bf16*)ctx,
                       (const bf16*)Wbf, d_in[5], d_in[7], d_in[9], d_in[11],
                       qp, kp, vp, d_out, (const int*)flag, 0);
    hipLaunchKernelGGL(transpose_v, dim3(16, 16, 4), dim3(256), 0, stream,
                       (const bf16*)vp, vT);
    hipLaunchKernelGGL(attn_mfma, dim3(512), dim3(512), 0, stream,
                       (const bf16*)qp, (const bf16*)kp, (const bf16*)vT,
                       d_in[12], d_in[13], ctx, av0, av1, (const int*)flag);
    hipLaunchKernelGGL(combine_av, dim3(4096), dim3(256), 0, stream,
                       (const bf16*)av0, (const bf16*)av1, d_out, (const int*)flag);
    hipLaunchKernelGGL(gemm_mfma, dim3(8, 32, 1), dim3(256), 0, stream,
                       (const bf16*)Abf_q, (const bf16*)Abf_k, (const bf16*)Abf_v, (const bf16*)ctx,
                       (const bf16*)Wbf, d_in[5], d_in[7], d_in[9], d_in[11],
                       qp, kp, vp, d_out, (const int*)flag, 1);
}